// Round 1
// 457.147 us; speedup vs baseline: 1.1409x; 1.1409x over previous
//
#include <hip/hip_runtime.h>
#include <math.h>

#define N_QDIM 256
#define N_EDIM 512
#define N_HEADS 8
#define N_HDIM 64
#define N_TOK 10
#define NJ 80   // N_HEADS * N_TOK

typedef short bf16x8 __attribute__((ext_vector_type(8)));
typedef float f32x4 __attribute__((ext_vector_type(4)));

// ---------------------------------------------------------------------------
// Precompute: keys_raw = tanh(embed) (10x64); K = keys_raw @ Wk.T (10x512);
// Ws[qd][j] = (1/8) sum_d Wq[h*64+d][qd] * K[t][h*64+d], j = h*10+t.
// Ws is emitted SPLIT into bf16 hi/lo and in MFMA *fragment order*:
//   frag element (kb, n, lane, e)  <-  Ws[kb*32 + 8*(lane>>4) + e][16*n + (lane&15)]
// so the main kernel's B loads are one coalesced 16B/lane read per fragment,
// and A/B use the same k-permutation (layout-exact independent of HW k map).
// 80 blocks x 256 threads: one fragment element per thread.
// ---------------------------------------------------------------------------
__global__ __launch_bounds__(256) void precompute_kernel(
    const float* __restrict__ embed, const float* __restrict__ Wq,
    const float* __restrict__ Wk, unsigned short* __restrict__ WfHi,
    unsigned short* __restrict__ WfLo, float* __restrict__ keysOut)
{
    __shared__ float skeys[N_TOK * N_HDIM];   // 640
    __shared__ float sK[N_TOK * N_EDIM];      // 5120
    const int tid = threadIdx.x;

    for (int i = tid; i < N_TOK * N_HDIM; i += 256) {
        float v = tanhf(embed[i]);
        skeys[i] = v;
        if (blockIdx.x == 0) keysOut[i] = v;
    }
    __syncthreads();

    for (int i = tid; i < N_TOK * N_EDIM; i += 256) {
        int t = i >> 9;          // / 512
        int e = i & 511;
        float s = 0.f;
        #pragma unroll
        for (int d = 0; d < N_HDIM; d++)
            s += skeys[t * N_HDIM + d] * Wk[e * N_HDIM + d];
        sK[i] = s;
    }
    __syncthreads();

    int flat = blockIdx.x * 256 + tid;   // 0..20479
    int e    = flat & 7;
    int lane = (flat >> 3) & 63;
    int rest = flat >> 9;                // 0..39
    int n    = rest % 5;
    int kb   = rest / 5;
    int c    = n * 16 + (lane & 15);     // score column j
    int h    = c / N_TOK;
    int t    = c - h * N_TOK;
    int qd   = kb * 32 + (lane >> 4) * 8 + e;

    float s = 0.f;
    #pragma unroll
    for (int d = 0; d < N_HDIM; d++)
        s += Wq[(h * N_HDIM + d) * N_QDIM + qd] * sK[t * N_EDIM + h * N_HDIM + d];
    s *= 0.125f;                         // fold 1/sqrt(64)

    // truncation split: s = hi + rem exactly; lo = bf16(rem)
    unsigned int u = __float_as_uint(s);
    float rem = s - __uint_as_float(u & 0xffff0000u);
    int idx = ((kb * 5 + n) * 64 + lane) * 8 + e;
    WfHi[idx] = (unsigned short)(u >> 16);
    WfLo[idx] = (unsigned short)(__float_as_uint(rem) >> 16);
}

// split 8 fp32 into bf16 hi/lo fragments (exact remainder; error ~2^-16 rel)
static __device__ __forceinline__ void splitFrag(float4 v0, float4 v1,
                                                 bf16x8& hi, bf16x8& lo)
{
    float x[8] = {v0.x, v0.y, v0.z, v0.w, v1.x, v1.y, v1.z, v1.w};
    #pragma unroll
    for (int e = 0; e < 8; e++) {
        unsigned u = __float_as_uint(x[e]);
        hi[e] = (short)(u >> 16);
        float r = x[e] - __uint_as_float(u & 0xffff0000u);
        lo[e] = (short)(__float_as_uint(r) >> 16);
    }
}

// ---------------------------------------------------------------------------
// Main: scores (Nx80) = inputs (Nx256) @ Ws (256x80) via split-bf16 MFMA
// (hi*hi + hi*lo + lo*hi), A fragments straight from global (no LDS, no
// barriers in the GEMM); then per-wave LDS bounce (16x84 half-tiles) for
// attn writes + out (Nx512) = per-head scores @ keys.
// 256 threads = 4 waves; wave owns 32 rows (2 M-tiles), all 80 cols (5 N-tiles).
// ---------------------------------------------------------------------------
__global__ __launch_bounds__(256, 4) void main_kernel(
    const float* __restrict__ inputs, const unsigned short* __restrict__ WfHi,
    const unsigned short* __restrict__ WfLo, const float* __restrict__ keys,
    float* __restrict__ outStyle, float* __restrict__ outAttn, int N)
{
    __shared__ float sS[4][16 * 84];     // per-wave 16x80 (pad 84) = 21504 B total

    const int tid = threadIdx.x;
    const int w   = tid >> 6;
    const int l   = tid & 63;
    const int l15 = l & 15;
    const int lg  = l >> 4;
    const int rowBase = blockIdx.x * 128 + w * 32;

    // A fragment pointers: row = rowBase + l15 (+16 for tile 1), k-off = 8*lg
    const float* pa0 = inputs + (size_t)(rowBase + l15) * N_QDIM + lg * 8;
    const float* pa1 = pa0 + 16 * N_QDIM;

    f32x4 acc[2][5];
    #pragma unroll
    for (int m = 0; m < 2; m++)
        #pragma unroll
        for (int n = 0; n < 5; n++)
            acc[m][n] = (f32x4){0.f, 0.f, 0.f, 0.f};

    #pragma unroll 2
    for (int kb = 0; kb < 8; kb++) {
        const float* p0 = pa0 + kb * 32;
        const float* p1 = pa1 + kb * 32;
        float4 x0 = *(const float4*)(p0);
        float4 x1 = *(const float4*)(p0 + 4);
        float4 y0 = *(const float4*)(p1);
        float4 y1 = *(const float4*)(p1 + 4);
        bf16x8 a0h, a0l, a1h, a1l;
        splitFrag(x0, x1, a0h, a0l);
        splitFrag(y0, y1, a1h, a1l);

        const unsigned short* bh = WfHi + kb * 2560 + l * 8;
        const unsigned short* bl = WfLo + kb * 2560 + l * 8;
        #pragma unroll
        for (int n = 0; n < 5; n++) {
            bf16x8 bhi = *(const bf16x8*)(bh + n * 512);
            bf16x8 blo = *(const bf16x8*)(bl + n * 512);
            acc[0][n] = __builtin_amdgcn_mfma_f32_16x16x32_bf16(a0h, bhi, acc[0][n], 0, 0, 0);
            acc[1][n] = __builtin_amdgcn_mfma_f32_16x16x32_bf16(a1h, bhi, acc[1][n], 0, 0, 0);
            acc[0][n] = __builtin_amdgcn_mfma_f32_16x16x32_bf16(a0l, bhi, acc[0][n], 0, 0, 0);
            acc[1][n] = __builtin_amdgcn_mfma_f32_16x16x32_bf16(a1l, bhi, acc[1][n], 0, 0, 0);
            acc[0][n] = __builtin_amdgcn_mfma_f32_16x16x32_bf16(a0h, blo, acc[0][n], 0, 0, 0);
            acc[1][n] = __builtin_amdgcn_mfma_f32_16x16x32_bf16(a1h, blo, acc[1][n], 0, 0, 0);
        }
    }

    // keys chunk (d = l15*4 .. +3) in registers, reused for all rows/heads
    float4 kr[N_TOK];
    #pragma unroll
    for (int t = 0; t < N_TOK; t++)
        kr[t] = *(const float4*)(keys + t * N_HDIM + l15 * 4);

    float* s = sS[w];

    #pragma unroll
    for (int m = 0; m < 2; m++) {
        // stage this M-tile's 16x80 scores: C/D frag row = 4*lg + r, col = 16n + l15
        #pragma unroll
        for (int n = 0; n < 5; n++)
            #pragma unroll
            for (int r = 0; r < 4; r++)
                s[(lg * 4 + r) * 84 + n * 16 + l15] = acc[m][n][r];
        __syncthreads();

        const int rStart = rowBase + m * 16;

        // attn_score [h][n][1][t]: per h, 160 contiguous floats for these rows
        #pragma unroll
        for (int h = 0; h < N_HEADS; h++) {
            float* dst = outAttn + ((size_t)h * N + rStart) * N_TOK;
            for (int i = l; i < 16 * N_TOK; i += 64) {
                int rr = i / N_TOK;
                int t  = i - rr * N_TOK;
                dst[i] = s[rr * 84 + h * N_TOK + t];
            }
        }

        // out[n][h*64+d] = sum_t s[row][h*10+t] * keys[t][d]
        #pragma unroll
        for (int i = 0; i < 4; i++) {
            int rr = i * 4 + lg;
            const float* srow = s + rr * 84;
            float* orow = outStyle + (size_t)(rStart + rr) * N_EDIM + l15 * 4;
            #pragma unroll
            for (int h = 0; h < N_HEADS; h++) {
                float4 o = {0.f, 0.f, 0.f, 0.f};
                #pragma unroll
                for (int t2 = 0; t2 < N_TOK; t2 += 2) {
                    float2 sc = *(const float2*)(srow + h * N_TOK + t2);
                    o.x += sc.x * kr[t2].x + sc.y * kr[t2 + 1].x;
                    o.y += sc.x * kr[t2].y + sc.y * kr[t2 + 1].y;
                    o.z += sc.x * kr[t2].z + sc.y * kr[t2 + 1].z;
                    o.w += sc.x * kr[t2].w + sc.y * kr[t2 + 1].w;
                }
                *(float4*)(orow + h * N_HDIM) = o;
            }
        }
        __syncthreads();
    }
}

extern "C" void kernel_launch(void* const* d_in, const int* in_sizes, int n_in,
                              void* d_out, int out_size, void* d_ws, size_t ws_size,
                              hipStream_t stream) {
    const float* inputs = (const float*)d_in[0];  // (N, 256)
    const float* embed  = (const float*)d_in[1];  // (10, 64)
    const float* Wq     = (const float*)d_in[2];  // (512, 256)
    const float* Wk     = (const float*)d_in[3];  // (512, 64)

    const int N = in_sizes[0] / N_QDIM;           // 131072

    // workspace: keys (640 f) | WfHi (20480 ushort) | WfLo (20480 ushort) = 84480 B
    float* keysWs = (float*)d_ws;
    unsigned short* WfHi = (unsigned short*)((char*)d_ws + 640 * sizeof(float));
    unsigned short* WfLo = WfHi + 8 * 5 * 64 * 8;

    float* outStyle = (float*)d_out;                        // N*512
    float* outAttn  = outStyle + (size_t)N * N_EDIM;        // 8*N*10

    precompute_kernel<<<80, 256, 0, stream>>>(embed, Wq, Wk, WfHi, WfLo, keysWs);
    main_kernel<<<N / 128, 256, 0, stream>>>(inputs, WfHi, WfLo, keysWs, outStyle, outAttn, N);
}